// Round 4
// baseline (87291.455 us; speedup 1.0000x reference)
//
#include <hip/hip_runtime.h>
#include <math.h>

#define F4(p) (*reinterpret_cast<const float4*>(p))

constexpr int D    = 512;
constexpr int H    = 8;
constexpr int HD   = 64;
constexpr int NL   = 6;
constexpr int NB   = 64;     // batch
constexpr int M    = 20;     // context length
constexpr int T    = 30;     // max_tokens
constexpr int SMAX = 49;     // 20 + 29 positions
constexpr int NR   = NB * M; // 1280 prefill rows
constexpr int NBLK = 64;     // decode grid
constexpr float EPS   = 1e-5f;
constexpr float SCALE = 0.125f; // 1/sqrt(64)

#define GM_PLAIN 0
#define GM_QKV   1

__device__ __forceinline__ float gelu_f(float x){
  return 0.5f * x * (1.f + erff(x * 0.70710678118654752f));
}

// -------------------- prefill kernels (unchanged) --------------------

__device__ __forceinline__ float wave_sum64(float v){
  #pragma unroll
  for (int o = 32; o > 0; o >>= 1) v += __shfl_down(v, o, 64);
  return v;
}

__device__ __forceinline__ float block_sum256(float v, float* red){
  v = wave_sum64(v);
  int wid = threadIdx.x >> 6, lane = threadIdx.x & 63;
  if (lane == 0) red[wid] = v;
  __syncthreads();
  if (threadIdx.x == 0) red[0] = red[0] + red[1] + red[2] + red[3];
  __syncthreads();
  float tot = red[0];
  __syncthreads();
  return tot;
}

__global__ __launch_bounds__(256) void k_embed(const float* __restrict__ ctx,
    const float* __restrict__ pos, float* __restrict__ X0){
  int r = blockIdx.x, t = threadIdx.x, s = r % M;
  X0[(size_t)r*D + t]       = ctx[(size_t)r*D + t]       + pos[(size_t)s*D + t];
  X0[(size_t)r*D + t + 256] = ctx[(size_t)r*D + t + 256] + pos[(size_t)s*D + t + 256];
}

__global__ __launch_bounds__(256) void k_ln(const float* __restrict__ x, float* __restrict__ y,
    const float* __restrict__ g, const float* __restrict__ bb){
  __shared__ float red[4];
  int r = blockIdx.x, t = threadIdx.x;
  const float* xr = x + (size_t)r*D;
  float v0 = xr[t], v1 = xr[t+256];
  float mean = block_sum256(v0+v1, red) * (1.f/D);
  float d0 = v0-mean, d1 = v1-mean;
  float var = block_sum256(d0*d0 + d1*d1, red) * (1.f/D);
  float rs = rsqrtf(var + EPS);
  float* yr = y + (size_t)r*D;
  yr[t]     = d0*rs*g[t]     + bb[t];
  yr[t+256] = d1*rs*g[t+256] + bb[t+256];
}

__global__ __launch_bounds__(256) void k_gemm(
    const float* __restrict__ A, const float* __restrict__ W,
    const float* __restrict__ bias, const float* __restrict__ res,
    float* __restrict__ C, int K, int ldc, int gelu_flag,
    float* __restrict__ q0, float* __restrict__ kc, float* __restrict__ vc, int mode){
  __shared__ __align__(16) float As[32][64];
  __shared__ __align__(16) float Ws[32][64];
  int m0 = blockIdx.x*64, n0 = blockIdx.y*64;
  int t = threadIdx.x, tx = t & 15, ty = t >> 4;
  float acc[4][4] = {};
  for (int k0 = 0; k0 < K; k0 += 32){
    #pragma unroll
    for (int i = 0; i < 2; i++){
      int idx = t + i*256;
      int m = idx & 63, k4 = idx >> 6;
      float4 a = F4(A + (size_t)(m0+m)*K + k0 + k4*4);
      As[k4*4+0][m]=a.x; As[k4*4+1][m]=a.y; As[k4*4+2][m]=a.z; As[k4*4+3][m]=a.w;
      float4 w = F4(W + (size_t)(n0+m)*K + k0 + k4*4);
      Ws[k4*4+0][m]=w.x; Ws[k4*4+1][m]=w.y; Ws[k4*4+2][m]=w.z; Ws[k4*4+3][m]=w.w;
    }
    __syncthreads();
    #pragma unroll
    for (int k = 0; k < 32; k++){
      float4 a = *reinterpret_cast<float4*>(&As[k][ty*4]);
      float4 w = *reinterpret_cast<float4*>(&Ws[k][tx*4]);
      float av[4] = {a.x,a.y,a.z,a.w};
      float wv[4] = {w.x,w.y,w.z,w.w};
      #pragma unroll
      for (int i = 0; i < 4; i++)
        #pragma unroll
        for (int jj = 0; jj < 4; jj++) acc[i][jj] += av[i]*wv[jj];
    }
    __syncthreads();
  }
  #pragma unroll
  for (int i = 0; i < 4; i++){
    int row = m0 + ty*4 + i;
    #pragma unroll
    for (int jj = 0; jj < 4; jj++){
      int col = n0 + tx*4 + jj;
      float v = acc[i][jj] + bias[col];
      if (res) v += res[(size_t)row*ldc + col];
      if (gelu_flag) v = gelu_f(v);
      if (mode == GM_PLAIN){
        C[(size_t)row*ldc + col] = v;
      } else {
        if (col < D) q0[(size_t)row*D + col] = v;
        else {
          int b = row / M, s = row % M;
          float* dst = (col < 2*D) ? kc : vc;
          dst[((size_t)b*SMAX + s)*D + (col & (D-1))] = v;
        }
      }
    }
  }
}

__global__ __launch_bounds__(256) void k_sattn_pre(const float* __restrict__ Q0,
    const float* __restrict__ kc, const float* __restrict__ vc, float* __restrict__ AT0){
  int b = blockIdx.x >> 3, h = blockIdx.x & 7, t = threadIdx.x;
  __shared__ __align__(16) float q[M][HD], kk[M][HD], vv[M][HD];
  __shared__ float sc[M][M];
  for (int idx = t; idx < M*HD; idx += 256){
    int s = idx >> 6, e = idx & 63;
    q[s][e]  = Q0[((size_t)b*M + s)*D + h*HD + e];
    kk[s][e] = kc[((size_t)b*SMAX + s)*D + h*HD + e];
    vv[s][e] = vc[((size_t)b*SMAX + s)*D + h*HD + e];
  }
  __syncthreads();
  for (int idx = t; idx < M*M; idx += 256){
    int qs = idx / M, ks = idx % M;
    if (ks <= qs){
      float s = 0.f;
      #pragma unroll
      for (int e = 0; e < HD; e++) s += q[qs][e]*kk[ks][e];
      sc[qs][ks] = s * SCALE;
    }
  }
  __syncthreads();
  if (t < M){
    float mx = -1e30f;
    for (int ks = 0; ks <= t; ks++) mx = fmaxf(mx, sc[t][ks]);
    float sum = 0.f;
    for (int ks = 0; ks <= t; ks++){ float e = expf(sc[t][ks]-mx); sc[t][ks] = e; sum += e; }
    float inv = 1.f/sum;
    for (int ks = 0; ks <= t; ks++) sc[t][ks] *= inv;
  }
  __syncthreads();
  for (int idx = t; idx < M*HD; idx += 256){
    int qs = idx >> 6, e = idx & 63;
    float o = 0.f;
    for (int ks = 0; ks <= qs; ks++) o += sc[qs][ks]*vv[ks][e];
    AT0[((size_t)b*M + qs)*D + h*HD + e] = o;
  }
}

__global__ __launch_bounds__(256) void k_cattn_pre(const float* __restrict__ Q0,
    const float* __restrict__ ckv, float* __restrict__ AT0){
  int b = blockIdx.x >> 3, h = blockIdx.x & 7, t = threadIdx.x;
  __shared__ __align__(16) float q[M][HD], kk[M][HD], vv[M][HD];
  __shared__ float sc[M][M];
  for (int idx = t; idx < M*HD; idx += 256){
    int s = idx >> 6, e = idx & 63;
    q[s][e]  = Q0[((size_t)b*M + s)*D + h*HD + e];
    kk[s][e] = ckv[((size_t)b*M + s)*1024 + h*HD + e];
    vv[s][e] = ckv[((size_t)b*M + s)*1024 + D + h*HD + e];
  }
  __syncthreads();
  for (int idx = t; idx < M*M; idx += 256){
    int qs = idx / M, ks = idx % M;
    float s = 0.f;
    #pragma unroll
    for (int e = 0; e < HD; e++) s += q[qs][e]*kk[ks][e];
    sc[qs][ks] = s * SCALE;
  }
  __syncthreads();
  if (t < M){
    float mx = -1e30f;
    for (int ks = 0; ks < M; ks++) mx = fmaxf(mx, sc[t][ks]);
    float sum = 0.f;
    for (int ks = 0; ks < M; ks++){ float e = expf(sc[t][ks]-mx); sc[t][ks] = e; sum += e; }
    float inv = 1.f/sum;
    for (int ks = 0; ks < M; ks++) sc[t][ks] *= inv;
  }
  __syncthreads();
  for (int idx = t; idx < M*HD; idx += 256){
    int qs = idx >> 6, e = idx & 63;
    float o = 0.f;
    for (int ks = 0; ks < M; ks++) o += sc[qs][ks]*vv[ks][e];
    AT0[((size_t)b*M + qs)*D + h*HD + e] = o;
  }
}

// -------------------- decode: persistent kernel, device-wide barrier --------------------

__device__ __forceinline__ void gsync(unsigned* cnt, unsigned* gen, unsigned target){
  __syncthreads();
  if (threadIdx.x == 0){
    __threadfence();
    unsigned a = __hip_atomic_fetch_add(cnt, 1u, __ATOMIC_ACQ_REL, __HIP_MEMORY_SCOPE_AGENT);
    if (a == NBLK - 1){
      __hip_atomic_store(cnt, 0u, __ATOMIC_RELAXED, __HIP_MEMORY_SCOPE_AGENT);
      __hip_atomic_store(gen, target, __ATOMIC_RELEASE, __HIP_MEMORY_SCOPE_AGENT);
    } else {
      while (__hip_atomic_load(gen, __ATOMIC_ACQUIRE, __HIP_MEMORY_SCOPE_AGENT) < target)
        __builtin_amdgcn_s_sleep(2);
    }
    __threadfence();
  }
  __syncthreads();
}

// column-parallel GEMV phase: block bk computes cols [bk*C, bk*C+C) for all 64 rows.
// MODE 0: dst[r*ldc+o] = v ; MODE 1: QKV scatter (q / kcache / vcache) ; MODE 2: X[r*512+o] += v
template<int C, int MODE, bool LN, bool GELU>
__device__ __forceinline__ void col_phase(
    const float* __restrict__ src,
    const float* __restrict__ wb, const float* __restrict__ bias,
    const float* __restrict__ g, const float* __restrict__ bb,
    float* __restrict__ dst, int ldc,
    float* __restrict__ qdst, float* __restrict__ kbp, float* __restrict__ vbp,
    float* __restrict__ X, int bk, int t)
{
  __shared__ __align__(16) float xs[16][520];
  const int j8 = t & 7, o0 = bk * C;
  #pragma unroll 1
  for (int tile = 0; tile < 4; tile++){
    { // stage 16 rows (one wave per row), LN applied inline
      int r = t >> 6, lane = t & 63;
      int rg = tile*16 + r;
      const float* sr = src + (size_t)rg*D + lane*8;
      float4 a = F4(sr), b4 = F4(sr + 4);
      float mval = 0.f, rsv = 1.f;
      if constexpr (LN){
        float s  = a.x+a.y+a.z+a.w + b4.x+b4.y+b4.z+b4.w;
        float s2 = a.x*a.x+a.y*a.y+a.z*a.z+a.w*a.w
                 + b4.x*b4.x+b4.y*b4.y+b4.z*b4.z+b4.w*b4.w;
        #pragma unroll
        for (int o = 32; o > 0; o >>= 1){ s += __shfl_xor(s,o,64); s2 += __shfl_xor(s2,o,64); }
        mval = s * (1.f/512.f);
        float var = s2 * (1.f/512.f) - mval*mval;
        rsv = rsqrtf(var + EPS);
      }
      float* xr = &xs[r][lane*8];
      if constexpr (LN){
        const float* gp = g + lane*8; const float* bp = bb + lane*8;
        float4 g0 = F4(gp), g1 = F4(gp+4), c0 = F4(bp), c1 = F4(bp+4);
        float4 o0v, o1v;
        o0v.x=(a.x -mval)*rsv*g0.x+c0.x; o0v.y=(a.y -mval)*rsv*g0.y+c0.y;
        o0v.z=(a.z -mval)*rsv*g0.z+c0.z; o0v.w=(a.w -mval)*rsv*g0.w+c0.w;
        o1v.x=(b4.x-mval)*rsv*g1.x+c1.x; o1v.y=(b4.y-mval)*rsv*g1.y+c1.y;
        o1v.z=(b4.z-mval)*rsv*g1.z+c1.z; o1v.w=(b4.w-mval)*rsv*g1.w+c1.w;
        *reinterpret_cast<float4*>(xr)   = o0v;
        *reinterpret_cast<float4*>(xr+4) = o1v;
      } else {
        *reinterpret_cast<float4*>(xr)   = a;
        *reinterpret_cast<float4*>(xr+4) = b4;
      }
    }
    __syncthreads();
    constexpr int NOUT = 16*C;           // divisible by 128 for C in {8,24,32}
    constexpr int PER  = NOUT / 128;
    #pragma unroll
    for (int i = 0; i < PER; i++){
      int oi = (t >> 3) + i*128;
      int c = oi >> 4, r = oi & 15;
      const float* w = wb + (size_t)(o0 + c)*D;
      const float* xr = xs[r];
      float a0 = 0.f, a1 = 0.f;
      #pragma unroll
      for (int u = 0; u < 8; u++){
        int d = j8*4 + u*64;
        float4 w0 = F4(w + d), w1 = F4(w + d + 32);
        float4 x0 = F4(xr + d), x1 = F4(xr + d + 32);
        a0 += w0.x*x0.x + w0.y*x0.y + w0.z*x0.z + w0.w*x0.w;
        a1 += w1.x*x1.x + w1.y*x1.y + w1.z*x1.z + w1.w*x1.w;
      }
      float a = a0 + a1;
      a += __shfl_xor(a,4,8); a += __shfl_xor(a,2,8); a += __shfl_xor(a,1,8);
      if (j8 == 0){
        int o = o0 + c, rg = tile*16 + r;
        float v = a + bias[o];
        if constexpr (GELU) v = gelu_f(v);
        if constexpr (MODE == 0){
          dst[(size_t)rg*ldc + o] = v;
        } else if constexpr (MODE == 1){
          if (o < D)            qdst[(size_t)rg*D + o] = v;
          else if (o < 2*D)     kbp[(size_t)rg*SMAX*D + (o - D)] = v;
          else                  vbp[(size_t)rg*SMAX*D + (o - 2*D)] = v;
        } else {
          X[(size_t)rg*D + o] += v;
        }
      }
    }
    __syncthreads();
  }
}

// FFN2: K=2048, C=8 cols/block, no LDS staging (hh rows via L1)
__device__ __forceinline__ void ffn2_phase(const float* __restrict__ HH,
    const float* __restrict__ wb, const float* __restrict__ bias,
    float* __restrict__ X, int bk, int t){
  int gp = t >> 3, j8 = t & 7;
  int r = gp >> 1, ch = gp & 1;
  const float* hrow = HH + (size_t)r*2048;
  #pragma unroll 1
  for (int ci = 0; ci < 4; ci++){
    int o = bk*8 + ch*4 + ci;
    const float* w = wb + (size_t)o*2048;
    float a0 = 0.f, a1 = 0.f;
    #pragma unroll 8
    for (int u = 0; u < 32; u++){
      int d = j8*4 + u*64;
      float4 w0 = F4(w + d), w1 = F4(w + d + 32);
      float4 x0 = F4(hrow + d), x1 = F4(hrow + d + 32);
      a0 += w0.x*x0.x + w0.y*x0.y + w0.z*x0.z + w0.w*x0.w;
      a1 += w1.x*x1.x + w1.y*x1.y + w1.z*x1.z + w1.w*x1.w;
    }
    float a = a0 + a1;
    a += __shfl_xor(a,4,8); a += __shfl_xor(a,2,8); a += __shfl_xor(a,1,8);
    if (j8 == 0) X[(size_t)r*D + o] += a + bias[o];
  }
}

// row-local attention: block = row. kb/vb = per-row base, kstride = row stride of keys.
__device__ __forceinline__ void attn_phase(const float* __restrict__ Q,
    const float* __restrict__ kb, const float* __restrict__ vb, size_t kstride,
    float* __restrict__ AT, int S, int bk, int t){
  __shared__ float sc[8*56];
  __shared__ float avp[1024];
  int gp = t >> 3, j8 = t & 7;
  {
    int h = gp >> 4, kslot = gp & 15;
    const float* qh = Q + (size_t)bk*D + h*HD + j8*4;
    float4 q0 = F4(qh), q1 = F4(qh + 32);
    for (int ks = kslot; ks < S; ks += 16){
      const float* kr = kb + (size_t)ks*kstride + h*HD + j8*4;
      float4 w0 = F4(kr), w1 = F4(kr + 32);
      float a = w0.x*q0.x + w0.y*q0.y + w0.z*q0.z + w0.w*q0.w
              + w1.x*q1.x + w1.y*q1.y + w1.z*q1.z + w1.w*q1.w;
      a += __shfl_xor(a,4,8); a += __shfl_xor(a,2,8); a += __shfl_xor(a,1,8);
      if (j8 == 0) sc[h*56 + ks] = a * SCALE;
    }
  }
  __syncthreads();
  if (t < 512){
    int h2 = t >> 6, lane = t & 63;
    float v = (lane < S) ? sc[h2*56 + lane] : -1e30f;
    float mx = v;
    #pragma unroll
    for (int o = 32; o > 0; o >>= 1) mx = fmaxf(mx, __shfl_xor(mx,o,64));
    float e = (lane < S) ? expf(v - mx) : 0.f;
    float sum = e;
    #pragma unroll
    for (int o = 32; o > 0; o >>= 1) sum += __shfl_xor(sum,o,64);
    if (lane < S) sc[h2*56 + lane] = e / sum;
  }
  __syncthreads();
  {
    int tt = t & 511, half = t >> 9;
    int h2 = tt >> 6, e = tt & 63;
    const float* vcol = vb + h2*HD + e;
    float o2 = 0.f;
    for (int ks = half; ks < S; ks += 2) o2 += sc[h2*56 + ks] * vcol[(size_t)ks*kstride];
    avp[half*512 + tt] = o2;
  }
  __syncthreads();
  if (t < 512) AT[(size_t)bk*D + t] = avp[t] + avp[512 + t];
}

// row-local: logits for step st, then x += pos[pn]
__device__ __forceinline__ void finalize_phase(float* __restrict__ X,
    const float* __restrict__ outw, const float* __restrict__ outb,
    const float* __restrict__ pos, float* __restrict__ out,
    int st, int pn, int bk, int t){
  int w = t >> 6, lane = t & 63;
  if (w < 8){
    const float* ww = outw + (size_t)w*D + lane*8;
    const float* xr = X + (size_t)bk*D + lane*8;
    float4 w0 = F4(ww), w1 = F4(ww + 4);
    float4 x0 = F4(xr), x1 = F4(xr + 4);
    float a = w0.x*x0.x + w0.y*x0.y + w0.z*x0.z + w0.w*x0.w
            + w1.x*x1.x + w1.y*x1.y + w1.z*x1.z + w1.w*x1.w;
    #pragma unroll
    for (int o = 32; o > 0; o >>= 1) a += __shfl_xor(a,o,64);
    if (lane == 0) out[((size_t)bk*T + st)*8 + w] = a + outb[w];
  }
  __syncthreads();
  if (t < D) X[(size_t)bk*D + t] += pos[(size_t)pn*D + t];
}

__global__ __launch_bounds__(1024, 1) void k_decode(
    const float* __restrict__ X0, const float* __restrict__ pos,
    const float* __restrict__ sa_w, const float* __restrict__ sa_b,
    const float* __restrict__ sa_ow, const float* __restrict__ sa_ob,
    const float* __restrict__ ca_w, const float* __restrict__ ca_b,
    const float* __restrict__ ca_ow, const float* __restrict__ ca_ob,
    const float* __restrict__ ln1g, const float* __restrict__ ln1b,
    const float* __restrict__ ln2g, const float* __restrict__ ln2b,
    const float* __restrict__ ln3g, const float* __restrict__ ln3b,
    const float* __restrict__ fw1, const float* __restrict__ fb1,
    const float* __restrict__ fw2, const float* __restrict__ fb2,
    const float* __restrict__ outw, const float* __restrict__ outb,
    float* __restrict__ kcache, float* __restrict__ vcache,
    const float* __restrict__ ckv, float* __restrict__ X,
    float* __restrict__ Q, float* __restrict__ AT, float* __restrict__ HH,
    unsigned* cnt, unsigned* gen, float* __restrict__ out)
{
  const int bk = blockIdx.x, t = threadIdx.x;
  unsigned tgt = 0;

  if (t < D) X[(size_t)bk*D + t] = X0[((size_t)bk*M + (M-1))*D + t];
  gsync(cnt, gen, ++tgt);
  finalize_phase(X, outw, outb, pos, out, 0, M, bk, t);
  gsync(cnt, gen, ++tgt);

  for (int st = 1; st < T; st++){
    const int p = M - 1 + st, S = p + 1;
    for (int l = 0; l < NL; l++){
      float* kbp = kcache + (size_t)l*NB*SMAX*D + (size_t)p*D;
      float* vbp = vcache + (size_t)l*NB*SMAX*D + (size_t)p*D;
      // LN1 + QKV (C=24)
      col_phase<24,1,true,false>(X, sa_w + (size_t)l*3*D*D, sa_b + l*3*D,
          ln1g + l*D, ln1b + l*D, nullptr, 0, Q, kbp, vbp, nullptr, bk, t);
      gsync(cnt, gen, ++tgt);
      // self-attn (row-local)
      attn_phase(Q, kcache + ((size_t)l*NB + bk)*SMAX*D,
                    vcache + ((size_t)l*NB + bk)*SMAX*D, D, AT, S, bk, t);
      gsync(cnt, gen, ++tgt);
      // out-proj (+res)
      col_phase<8,2,false,false>(AT, sa_ow + (size_t)l*D*D, sa_ob + l*D,
          nullptr, nullptr, nullptr, 0, nullptr, nullptr, nullptr, X, bk, t);
      gsync(cnt, gen, ++tgt);
      // LN2 + cross-q
      col_phase<8,0,true,false>(X, ca_w + (size_t)l*3*D*D, ca_b + l*3*D,
          ln2g + l*D, ln2b + l*D, Q, D, nullptr, nullptr, nullptr, nullptr, bk, t);
      gsync(cnt, gen, ++tgt);
      // cross-attn (row-local)
      {
        const float* cb_ = ckv + ((size_t)l*NB + bk)*M*1024;
        attn_phase(Q, cb_, cb_ + D, 1024, AT, M, bk, t);
      }
      gsync(cnt, gen, ++tgt);
      // cross out-proj (+res)
      col_phase<8,2,false,false>(AT, ca_ow + (size_t)l*D*D, ca_ob + l*D,
          nullptr, nullptr, nullptr, 0, nullptr, nullptr, nullptr, X, bk, t);
      gsync(cnt, gen, ++tgt);
      // LN3 + FFN1 + GELU (C=32)
      col_phase<32,0,true,true>(X, fw1 + (size_t)l*2048*D, fb1 + l*2048,
          ln3g + l*D, ln3b + l*D, HH, 2048, nullptr, nullptr, nullptr, nullptr, bk, t);
      gsync(cnt, gen, ++tgt);
      // FFN2 (+res)
      ffn2_phase(HH, fw2 + (size_t)l*D*2048, fb2 + l*D, X, bk, t);
      gsync(cnt, gen, ++tgt);
    }
    finalize_phase(X, outw, outb, pos, out, st, M + st, bk, t);
    gsync(cnt, gen, ++tgt);
  }
}

// -------------------- host --------------------

extern "C" void kernel_launch(void* const* d_in, const int* in_sizes, int n_in,
                              void* d_out, int out_size, void* d_ws, size_t ws_size,
                              hipStream_t stream){
  (void)in_sizes; (void)n_in; (void)out_size; (void)ws_size;
  const float* ctx   = (const float*)d_in[0];
  const float* pos   = (const float*)d_in[1];
  const float* sa_w  = (const float*)d_in[2];
  const float* sa_b  = (const float*)d_in[3];
  const float* sa_ow = (const float*)d_in[4];
  const float* sa_ob = (const float*)d_in[5];
  const float* ca_w  = (const float*)d_in[6];
  const float* ca_b  = (const float*)d_in[7];
  const float* ca_ow = (const float*)d_in[8];
  const float* ca_ob = (const float*)d_in[9];
  const float* ln1g  = (const float*)d_in[10];
  const float* ln1b  = (const float*)d_in[11];
  const float* ln2g  = (const float*)d_in[12];
  const float* ln2b  = (const float*)d_in[13];
  const float* ln3g  = (const float*)d_in[14];
  const float* ln3b  = (const float*)d_in[15];
  const float* fw1   = (const float*)d_in[16];
  const float* fb1   = (const float*)d_in[17];
  const float* fw2   = (const float*)d_in[18];
  const float* fb2   = (const float*)d_in[19];
  const float* outw  = (const float*)d_in[20];
  const float* outb  = (const float*)d_in[21];
  float* out = (float*)d_out;

  float* w = (float*)d_ws;
  size_t off = 0;
  auto alloc = [&](size_t n){ float* p = w + off; off += n; return p; };
  float* kcache = alloc((size_t)NL*NB*SMAX*D);
  float* vcache = alloc((size_t)NL*NB*SMAX*D);
  float* ckv    = alloc((size_t)NL*NB*M*1024);
  float* X0     = alloc((size_t)NR*D);
  float* XN0    = alloc((size_t)NR*D);
  float* Q0     = alloc((size_t)NR*D);
  float* AT0    = alloc((size_t)NR*D);
  float* H0     = alloc((size_t)NR*2048);
  float* Xd     = alloc((size_t)NB*D);
  float* Qd     = alloc((size_t)NB*D);
  float* ATd    = alloc((size_t)NB*D);
  float* HHd    = alloc((size_t)NB*2048);
  unsigned* bar = (unsigned*)(w + off); off += 256;   // 1 KB barrier region

  hipMemsetAsync(bar, 0, 1024, stream);

  dim3 blk(256);

  // embed + one-time cross K/V for all layers
  k_embed<<<NR, blk, 0, stream>>>(ctx, pos, X0);
  for (int l = 0; l < NL; l++){
    k_gemm<<<dim3(NR/64, 1024/64), blk, 0, stream>>>(
        ctx, ca_w + (size_t)l*3*D*D + (size_t)D*D, ca_b + (size_t)l*3*D + D, nullptr,
        ckv + (size_t)l*NB*M*1024, 512, 1024, 0, nullptr, nullptr, nullptr, GM_PLAIN);
  }

  // ---- prefill ----
  for (int l = 0; l < NL; l++){
    const float* saw = sa_w + (size_t)l*3*D*D;
    const float* sab = sa_b + (size_t)l*3*D;
    float* kcl = kcache + (size_t)l*NB*SMAX*D;
    float* vcl = vcache + (size_t)l*NB*SMAX*D;
    const float* ckl = ckv + (size_t)l*NB*M*1024;

    k_ln<<<NR, blk, 0, stream>>>(X0, XN0, ln1g + l*D, ln1b + l*D);
    k_gemm<<<dim3(NR/64, 1536/64), blk, 0, stream>>>(
        XN0, saw, sab, nullptr, nullptr, 512, D, 0, Q0, kcl, vcl, GM_QKV);
    k_sattn_pre<<<NB*H, blk, 0, stream>>>(Q0, kcl, vcl, AT0);
    k_gemm<<<dim3(NR/64, D/64), blk, 0, stream>>>(
        AT0, sa_ow + (size_t)l*D*D, sa_ob + l*D, X0, X0, 512, D, 0,
        nullptr, nullptr, nullptr, GM_PLAIN);
    k_ln<<<NR, blk, 0, stream>>>(X0, XN0, ln2g + l*D, ln2b + l*D);
    k_gemm<<<dim3(NR/64, D/64), blk, 0, stream>>>(
        XN0, ca_w + (size_t)l*3*D*D, ca_b + (size_t)l*3*D, nullptr, Q0, 512, D, 0,
        nullptr, nullptr, nullptr, GM_PLAIN);
    k_cattn_pre<<<NB*H, blk, 0, stream>>>(Q0, ckl, AT0);
    k_gemm<<<dim3(NR/64, D/64), blk, 0, stream>>>(
        AT0, ca_ow + (size_t)l*D*D, ca_ob + l*D, X0, X0, 512, D, 0,
        nullptr, nullptr, nullptr, GM_PLAIN);
    k_ln<<<NR, blk, 0, stream>>>(X0, XN0, ln3g + l*D, ln3b + l*D);
    k_gemm<<<dim3(NR/64, 2048/64), blk, 0, stream>>>(
        XN0, fw1 + (size_t)l*2048*D, fb1 + (size_t)l*2048, nullptr, H0, 512, 2048, 1,
        nullptr, nullptr, nullptr, GM_PLAIN);
    k_gemm<<<dim3(NR/64, D/64), blk, 0, stream>>>(
        H0, fw2 + (size_t)l*D*2048, fb2 + l*D, X0, X0, 2048, D, 0,
        nullptr, nullptr, nullptr, GM_PLAIN);
  }

  // ---- decode: single persistent kernel with device-wide phase barriers ----
  k_decode<<<NBLK, dim3(1024), 0, stream>>>(
      X0, pos, sa_w, sa_b, sa_ow, sa_ob, ca_w, ca_b, ca_ow, ca_ob,
      ln1g, ln1b, ln2g, ln2b, ln3g, ln3b, fw1, fb1, fw2, fb2,
      outw, outb, kcache, vcache, ckv, Xd, Qd, ATd, HHd,
      bar, bar + 64, out);
}

// Round 5
// 74119.025 us; speedup vs baseline: 1.1777x; 1.1777x over previous
//
#include <hip/hip_runtime.h>
#include <math.h>

#define F4(p) (*reinterpret_cast<const float4*>(p))
#define AGENT __HIP_MEMORY_SCOPE_AGENT

constexpr int D    = 512;
constexpr int H    = 8;
constexpr int HD   = 64;
constexpr int NL   = 6;
constexpr int NB   = 64;     // batch
constexpr int M    = 20;     // context length
constexpr int T    = 30;     // max_tokens
constexpr int SMAX = 49;
constexpr int NR   = NB * M;
constexpr int NBLK = 128;    // decode grid
constexpr int XS   = 544;    // LDS row stride (floats): 136%32==8 -> 2-way-free banks
constexpr float EPS   = 1e-5f;
constexpr float SCALE = 0.125f;

#define GM_PLAIN 0
#define GM_QKV   1

__device__ __forceinline__ float gelu_f(float x){
  return 0.5f * x * (1.f + erff(x * 0.70710678118654752f));
}

// -------------------- prefill kernels (unchanged, verified) --------------------

__device__ __forceinline__ float wave_sum64(float v){
  #pragma unroll
  for (int o = 32; o > 0; o >>= 1) v += __shfl_down(v, o, 64);
  return v;
}

__device__ __forceinline__ float block_sum256(float v, float* red){
  v = wave_sum64(v);
  int wid = threadIdx.x >> 6, lane = threadIdx.x & 63;
  if (lane == 0) red[wid] = v;
  __syncthreads();
  if (threadIdx.x == 0) red[0] = red[0] + red[1] + red[2] + red[3];
  __syncthreads();
  float tot = red[0];
  __syncthreads();
  return tot;
}

__global__ __launch_bounds__(256) void k_embed(const float* __restrict__ ctx,
    const float* __restrict__ pos, float* __restrict__ X0){
  int r = blockIdx.x, t = threadIdx.x, s = r % M;
  X0[(size_t)r*D + t]       = ctx[(size_t)r*D + t]       + pos[(size_t)s*D + t];
  X0[(size_t)r*D + t + 256] = ctx[(size_t)r*D + t + 256] + pos[(size_t)s*D + t + 256];
}

__global__ __launch_bounds__(256) void k_ln(const float* __restrict__ x, float* __restrict__ y,
    const float* __restrict__ g, const float* __restrict__ bb){
  __shared__ float red[4];
  int r = blockIdx.x, t = threadIdx.x;
  const float* xr = x + (size_t)r*D;
  float v0 = xr[t], v1 = xr[t+256];
  float mean = block_sum256(v0+v1, red) * (1.f/D);
  float d0 = v0-mean, d1 = v1-mean;
  float var = block_sum256(d0*d0 + d1*d1, red) * (1.f/D);
  float rs = rsqrtf(var + EPS);
  float* yr = y + (size_t)r*D;
  yr[t]     = d0*rs*g[t]     + bb[t];
  yr[t+256] = d1*rs*g[t+256] + bb[t+256];
}

__global__ __launch_bounds__(256) void k_gemm(
    const float* __restrict__ A, const float* __restrict__ W,
    const float* __restrict__ bias, const float* __restrict__ res,
    float* __restrict__ C, int K, int ldc, int gelu_flag,
    float* __restrict__ q0, float* __restrict__ kc, float* __restrict__ vc, int mode){
  __shared__ __align__(16) float As[32][64];
  __shared__ __align__(16) float Ws[32][64];
  int m0 = blockIdx.x*64, n0 = blockIdx.y*64;
  int t = threadIdx.x, tx = t & 15, ty = t >> 4;
  float acc[4][4] = {};
  for (int k0 = 0; k0 < K; k0 += 32){
    #pragma unroll
    for (int i = 0; i < 2; i++){
      int idx = t + i*256;
      int m = idx & 63, k4 = idx >> 6;
      float4 a = F4(A + (size_t)(m0+m)*K + k0 + k4*4);
      As[k4*4+0][m]=a.x; As[k4*4+1][m]=a.y; As[k4*4+2][m]=a.z; As[k4*4+3][m]=a.w;
      float4 w = F4(W + (size_t)(n0+m)*K + k0 + k4*4);
      Ws[k4*4+0][m]=w.x; Ws[k4*4+1][m]=w.y; Ws[k4*4+2][m]=w.z; Ws[k4*4+3][m]=w.w;
    }
    __syncthreads();
    #pragma unroll
    for (int k = 0; k < 32; k++){
      float4 a = *reinterpret_cast<float4*>(&As[k][ty*4]);
      float4 w = *reinterpret_cast<float4*>(&Ws[k][tx*4]);
      float av[4] = {a.x,a.y,a.z,a.w};
      float wv[4] = {w.x,w.y,w.z,w.w};
      #pragma unroll
      for (int i = 0; i < 4; i++)
        #pragma unroll
        for (int jj = 0; jj < 4; jj++) acc[i][jj] += av[i]*wv[jj];
    }
    __syncthreads();
  }
  #pragma unroll
  for (int i = 0; i < 4; i++){
    int row = m0 + ty*4 + i;
    #pragma unroll
    for (int jj = 0; jj < 4; jj++){
      int col = n0 + tx*4 + jj;
      float v = acc[i][jj] + bias[col];
      if (res) v += res[(size_t)row*ldc + col];
      if (gelu_flag) v = gelu_f(v);
      if (mode == GM_PLAIN){
        C[(size_t)row*ldc + col] = v;
      } else {
        if (col < D) q0[(size_t)row*D + col] = v;
        else {
          int b = row / M, s = row % M;
          float* dst = (col < 2*D) ? kc : vc;
          dst[((size_t)b*SMAX + s)*D + (col & (D-1))] = v;
        }
      }
    }
  }
}

__global__ __launch_bounds__(256) void k_sattn_pre(const float* __restrict__ Q0,
    const float* __restrict__ kc, const float* __restrict__ vc, float* __restrict__ AT0){
  int b = blockIdx.x >> 3, h = blockIdx.x & 7, t = threadIdx.x;
  __shared__ __align__(16) float q[M][HD], kk[M][HD], vv[M][HD];
  __shared__ float sc[M][M];
  for (int idx = t; idx < M*HD; idx += 256){
    int s = idx >> 6, e = idx & 63;
    q[s][e]  = Q0[((size_t)b*M + s)*D + h*HD + e];
    kk[s][e] = kc[((size_t)b*SMAX + s)*D + h*HD + e];
    vv[s][e] = vc[((size_t)b*SMAX + s)*D + h*HD + e];
  }
  __syncthreads();
  for (int idx = t; idx < M*M; idx += 256){
    int qs = idx / M, ks = idx % M;
    if (ks <= qs){
      float s = 0.f;
      #pragma unroll
      for (int e = 0; e < HD; e++) s += q[qs][e]*kk[ks][e];
      sc[qs][ks] = s * SCALE;
    }
  }
  __syncthreads();
  if (t < M){
    float mx = -1e30f;
    for (int ks = 0; ks <= t; ks++) mx = fmaxf(mx, sc[t][ks]);
    float sum = 0.f;
    for (int ks = 0; ks <= t; ks++){ float e = expf(sc[t][ks]-mx); sc[t][ks] = e; sum += e; }
    float inv = 1.f/sum;
    for (int ks = 0; ks <= t; ks++) sc[t][ks] *= inv;
  }
  __syncthreads();
  for (int idx = t; idx < M*HD; idx += 256){
    int qs = idx >> 6, e = idx & 63;
    float o = 0.f;
    for (int ks = 0; ks <= qs; ks++) o += sc[qs][ks]*vv[ks][e];
    AT0[((size_t)b*M + qs)*D + h*HD + e] = o;
  }
}

__global__ __launch_bounds__(256) void k_cattn_pre(const float* __restrict__ Q0,
    const float* __restrict__ ckv, float* __restrict__ AT0){
  int b = blockIdx.x >> 3, h = blockIdx.x & 7, t = threadIdx.x;
  __shared__ __align__(16) float q[M][HD], kk[M][HD], vv[M][HD];
  __shared__ float sc[M][M];
  for (int idx = t; idx < M*HD; idx += 256){
    int s = idx >> 6, e = idx & 63;
    q[s][e]  = Q0[((size_t)b*M + s)*D + h*HD + e];
    kk[s][e] = ckv[((size_t)b*M + s)*1024 + h*HD + e];
    vv[s][e] = ckv[((size_t)b*M + s)*1024 + D + h*HD + e];
  }
  __syncthreads();
  for (int idx = t; idx < M*M; idx += 256){
    int qs = idx / M, ks = idx % M;
    float s = 0.f;
    #pragma unroll
    for (int e = 0; e < HD; e++) s += q[qs][e]*kk[ks][e];
    sc[qs][ks] = s * SCALE;
  }
  __syncthreads();
  if (t < M){
    float mx = -1e30f;
    for (int ks = 0; ks < M; ks++) mx = fmaxf(mx, sc[t][ks]);
    float sum = 0.f;
    for (int ks = 0; ks < M; ks++){ float e = expf(sc[t][ks]-mx); sc[t][ks] = e; sum += e; }
    float inv = 1.f/sum;
    for (int ks = 0; ks < M; ks++) sc[t][ks] *= inv;
  }
  __syncthreads();
  for (int idx = t; idx < M*HD; idx += 256){
    int qs = idx >> 6, e = idx & 63;
    float o = 0.f;
    for (int ks = 0; ks < M; ks++) o += sc[qs][ks]*vv[ks][e];
    AT0[((size_t)b*M + qs)*D + h*HD + e] = o;
  }
}

// -------------------- decode v2: column-parallel with LDS-wide X staging --------------------

// hierarchical barrier: 8 sub-counters (16 blocks each) -> master -> gen broadcast.
// sub[i]=bar[i*16], master=bar[128], gen=bar[144]
__device__ __forceinline__ void gsync(unsigned* bar, unsigned target){
  __syncthreads();
  if (threadIdx.x == 0){
    __threadfence();
    int s = blockIdx.x >> 4;
    unsigned a = __hip_atomic_fetch_add(bar + s*16, 1u, __ATOMIC_ACQ_REL, AGENT);
    if (a == 15u){
      unsigned m = __hip_atomic_fetch_add(bar + 128, 1u, __ATOMIC_ACQ_REL, AGENT);
      if (m == 7u){
        #pragma unroll
        for (int i = 0; i < 8; i++)
          __hip_atomic_store(bar + i*16, 0u, __ATOMIC_RELAXED, AGENT);
        __hip_atomic_store(bar + 128, 0u, __ATOMIC_RELAXED, AGENT);
        __hip_atomic_store(bar + 144, target, __ATOMIC_RELEASE, AGENT);
      }
    }
    while (__hip_atomic_load(bar + 144, __ATOMIC_ACQUIRE, AGENT) < target)
      __builtin_amdgcn_s_sleep(2);
    __threadfence();
  }
  __syncthreads();
}

// stage 64 rows (row stride srs) into LB[r*XS], optional LN. 512 threads: wave w does rows w,w+8,...
template<bool LN>
__device__ __forceinline__ void stage_x(const float* __restrict__ src, int srs,
    const float* __restrict__ g, const float* __restrict__ bb, float* LB, int t){
  int w = t >> 6, lane = t & 63;
  #pragma unroll 1
  for (int r = w; r < 64; r += 8){
    const float* sr = src + (size_t)r*srs + lane*8;
    float4 a = F4(sr), b4 = F4(sr+4);
    if constexpr (LN){
      float s  = a.x+a.y+a.z+a.w + b4.x+b4.y+b4.z+b4.w;
      float s2 = a.x*a.x+a.y*a.y+a.z*a.z+a.w*a.w
               + b4.x*b4.x+b4.y*b4.y+b4.z*b4.z+b4.w*b4.w;
      #pragma unroll
      for (int o = 32; o > 0; o >>= 1){ s += __shfl_xor(s,o,64); s2 += __shfl_xor(s2,o,64); }
      float m = s * (1.f/512.f);
      float rsv = rsqrtf(s2 * (1.f/512.f) - m*m + EPS);
      const float* gp = g + lane*8; const float* bp = bb + lane*8;
      float4 g0 = F4(gp), g1 = F4(gp+4), c0 = F4(bp), c1 = F4(bp+4);
      a.x=(a.x-m)*rsv*g0.x+c0.x; a.y=(a.y-m)*rsv*g0.y+c0.y;
      a.z=(a.z-m)*rsv*g0.z+c0.z; a.w=(a.w-m)*rsv*g0.w+c0.w;
      b4.x=(b4.x-m)*rsv*g1.x+c1.x; b4.y=(b4.y-m)*rsv*g1.y+c1.y;
      b4.z=(b4.z-m)*rsv*g1.z+c1.z; b4.w=(b4.w-m)*rsv*g1.w+c1.w;
    }
    float* xr = LB + r*XS + lane*8;
    *reinterpret_cast<float4*>(xr)   = a;
    *reinterpret_cast<float4*>(xr+4) = b4;
  }
}

// Column-parallel GEMV: block owns CN cols at o0; each 8-lane group owns one row r=w*8+g8,
// iterates col-chunks of 4; W-row loads are wave-broadcast (one 128B fetch/instr).
// MODE 0: dst[r*drs+o]=v  MODE 1: QKV scatter  MODE 2: X[r*D+o]+=v  MODE 3: atomicAdd X
template<int CN, int MODE, bool LN, bool GELU>
__device__ __forceinline__ void col_phase(
    const float* __restrict__ src, int srs,
    const float* __restrict__ wb, int wrs, int o0,
    const float* __restrict__ bias, bool addbias,
    const float* __restrict__ g, const float* __restrict__ bb,
    float* __restrict__ dst, int drs,
    float* __restrict__ qd, float* __restrict__ kb, float* __restrict__ vb, int p,
    float* __restrict__ X, float* LB, int t)
{
  stage_x<LN>(src, srs, g, bb, LB, t);
  __syncthreads();
  const int w = t >> 6, lane = t & 63, g8 = lane >> 3, j8 = t & 7;
  const int r = w*8 + g8;
  const float* xr = LB + r*XS;
  #pragma unroll
  for (int c0 = 0; c0 < CN; c0 += 4){
    const float* w0 = wb + (size_t)(o0 + c0    )*wrs;
    const float* w1 = wb + (size_t)(o0 + c0 + 1)*wrs;
    const float* w2 = wb + (size_t)(o0 + c0 + 2)*wrs;
    const float* w3 = wb + (size_t)(o0 + c0 + 3)*wrs;
    float a0=0.f, a1=0.f, a2=0.f, a3=0.f;
    #pragma unroll
    for (int u = 0; u < 16; u++){
      int d = u*32 + j8*4;
      float4 xv = *reinterpret_cast<const float4*>(xr + d);
      float4 v0 = F4(w0+d); a0 += v0.x*xv.x+v0.y*xv.y+v0.z*xv.z+v0.w*xv.w;
      float4 v1 = F4(w1+d); a1 += v1.x*xv.x+v1.y*xv.y+v1.z*xv.z+v1.w*xv.w;
      float4 v2 = F4(w2+d); a2 += v2.x*xv.x+v2.y*xv.y+v2.z*xv.z+v2.w*xv.w;
      float4 v3 = F4(w3+d); a3 += v3.x*xv.x+v3.y*xv.y+v3.z*xv.z+v3.w*xv.w;
    }
    a0 += __shfl_xor(a0,4,8); a0 += __shfl_xor(a0,2,8); a0 += __shfl_xor(a0,1,8);
    a1 += __shfl_xor(a1,4,8); a1 += __shfl_xor(a1,2,8); a1 += __shfl_xor(a1,1,8);
    a2 += __shfl_xor(a2,4,8); a2 += __shfl_xor(a2,2,8); a2 += __shfl_xor(a2,1,8);
    a3 += __shfl_xor(a3,4,8); a3 += __shfl_xor(a3,2,8); a3 += __shfl_xor(a3,1,8);
    if (j8 < 4){
      float v = (j8==0)?a0:(j8==1)?a1:(j8==2)?a2:a3;
      int o = o0 + c0 + j8;
      if (addbias) v += bias[o];
      if constexpr (GELU) v = gelu_f(v);
      if constexpr (MODE == 0){
        dst[(size_t)r*drs + o] = v;
      } else if constexpr (MODE == 1){
        if (o < D)            qd[(size_t)r*D + o] = v;
        else if (o < 2*D)     kb[((size_t)r*SMAX + p)*D + (o - D)]   = v;
        else                  vb[((size_t)r*SMAX + p)*D + (o - 2*D)] = v;
      } else if constexpr (MODE == 2){
        X[(size_t)r*D + o] += v;
      } else {
        atomicAdd(&X[(size_t)r*D + o], v);
      }
    }
  }
}

// attention: block bk -> row r=bk>>1, head-half hh=bk&1 (4 heads). 512 threads.
__device__ __forceinline__ void attn2(const float* __restrict__ Qd,
    const float* __restrict__ kb, const float* __restrict__ vb, int kstride, int S,
    float* __restrict__ AT, int r, int hh, float* LB, int t){
  float* sc  = LB;        // 4*64
  float* avp = LB + 512;  // 512
  int j8 = t & 7;
  {
    int hl = t >> 7, kslot = (t & 127) >> 3;
    const float* qh = Qd + (size_t)r*D + (hh*4+hl)*HD;
    float4 q0 = F4(qh + j8*4), q1 = F4(qh + j8*4 + 32);
    for (int ks = kslot; ks < S; ks += 16){
      const float* kr = kb + (size_t)ks*kstride + (hh*4+hl)*HD;
      float4 w0 = F4(kr + j8*4), w1 = F4(kr + j8*4 + 32);
      float a = w0.x*q0.x + w0.y*q0.y + w0.z*q0.z + w0.w*q0.w
              + w1.x*q1.x + w1.y*q1.y + w1.z*q1.z + w1.w*q1.w;
      a += __shfl_xor(a,4,8); a += __shfl_xor(a,2,8); a += __shfl_xor(a,1,8);
      if (j8 == 0) sc[hl*64 + ks] = a * SCALE;
    }
  }
  __syncthreads();
  if (t < 256){
    int hl = t >> 6, lane = t & 63;
    float v = (lane < S) ? sc[hl*64 + lane] : -1e30f;
    float mx = v;
    #pragma unroll
    for (int o = 32; o > 0; o >>= 1) mx = fmaxf(mx, __shfl_xor(mx,o,64));
    float e = (lane < S) ? expf(v - mx) : 0.f;
    float sum = e;
    #pragma unroll
    for (int o = 32; o > 0; o >>= 1) sum += __shfl_xor(sum,o,64);
    if (lane < S) sc[hl*64 + lane] = e / sum;
  }
  __syncthreads();
  {
    int tt = t & 255, half = t >> 8;
    int hl = tt >> 6, e = tt & 63;
    const float* vcol = vb + (hh*4+hl)*HD + e;
    float o2 = 0.f;
    for (int ks = half; ks < S; ks += 2) o2 += sc[hl*64 + ks] * vcol[(size_t)ks*kstride];
    avp[half*256 + tt] = o2;
  }
  __syncthreads();
  if (t < 256) AT[(size_t)r*D + hh*256 + t] = avp[t] + avp[256 + t];
}

__device__ __forceinline__ void fin2(float* __restrict__ X,
    const float* __restrict__ outw, const float* __restrict__ outb,
    const float* __restrict__ pos, float* __restrict__ out,
    int st, int pn, int r, bool act, int t){
  if (act){
    int c = t >> 6, lane = t & 63;
    const float* ww = outw + (size_t)c*D + lane*8;
    const float* xr = X + (size_t)r*D + lane*8;
    float4 w0 = F4(ww), w1 = F4(ww + 4);
    float4 x0 = F4(xr), x1 = F4(xr + 4);
    float a = w0.x*x0.x + w0.y*x0.y + w0.z*x0.z + w0.w*x0.w
            + w1.x*x1.x + w1.y*x1.y + w1.z*x1.z + w1.w*x1.w;
    #pragma unroll
    for (int o = 32; o > 0; o >>= 1) a += __shfl_xor(a,o,64);
    if (lane == 0) out[((size_t)r*T + st)*8 + c] = a + outb[c];
  }
  __syncthreads();
  if (act) X[(size_t)r*D + t] += pos[(size_t)pn*D + t];
}

__global__ __launch_bounds__(512, 1) void k_decode(
    const float* __restrict__ X0, const float* __restrict__ pos,
    const float* __restrict__ sa_w, const float* __restrict__ sa_b,
    const float* __restrict__ sa_ow, const float* __restrict__ sa_ob,
    const float* __restrict__ ca_w, const float* __restrict__ ca_b,
    const float* __restrict__ ca_ow, const float* __restrict__ ca_ob,
    const float* __restrict__ ln1g, const float* __restrict__ ln1b,
    const float* __restrict__ ln2g, const float* __restrict__ ln2b,
    const float* __restrict__ ln3g, const float* __restrict__ ln3b,
    const float* __restrict__ fw1, const float* __restrict__ fb1,
    const float* __restrict__ fw2, const float* __restrict__ fb2,
    const float* __restrict__ outw, const float* __restrict__ outb,
    float* __restrict__ kcache, float* __restrict__ vcache,
    const float* __restrict__ ckv, float* __restrict__ X,
    float* __restrict__ Qd, float* __restrict__ ATd, float* __restrict__ HH,
    unsigned* bar, float* __restrict__ out)
{
  __shared__ __align__(16) float LB[64*XS];   // 139264 B
  const int bk = blockIdx.x, t = threadIdx.x;
  const bool actrow = (bk < NB);
  const int r_at = bk >> 1, hh = bk & 1;
  unsigned tgt = 0;

  if (actrow) X[(size_t)bk*D + t] = X0[((size_t)bk*M + (M-1))*D + t];
  gsync(bar, ++tgt);
  fin2(X, outw, outb, pos, out, 0, M, bk, actrow, t);
  gsync(bar, ++tgt);

  for (int st = 1; st < T; st++){
    const int p = M - 1 + st, S = p + 1;
    for (int l = 0; l < NL; l++){
      float* kcl = kcache + (size_t)l*NB*SMAX*D;
      float* vcl = vcache + (size_t)l*NB*SMAX*D;
      const float* cb_ = ckv + ((size_t)l*NB + r_at)*M*1024;

      // 1: LN1 + QKV (CN=12)
      col_phase<12,1,true,false>(X, D, sa_w + (size_t)l*3*D*D, D, bk*12,
          sa_b + (size_t)l*3*D, true, ln1g + l*D, ln1b + l*D,
          nullptr, 0, Qd, kcl, vcl, p, nullptr, LB, t);
      gsync(bar, ++tgt);
      // 2: self-attn
      attn2(Qd, kcl + (size_t)r_at*SMAX*D, vcl + (size_t)r_at*SMAX*D, D, S, ATd, r_at, hh, LB, t);
      gsync(bar, ++tgt);
      // 3: out-proj + res (CN=4)
      col_phase<4,2,false,false>(ATd, D, sa_ow + (size_t)l*D*D, D, bk*4,
          sa_ob + (size_t)l*D, true, nullptr, nullptr,
          nullptr, 0, nullptr, nullptr, nullptr, 0, X, LB, t);
      gsync(bar, ++tgt);
      // 4: LN2 + cross-q (CN=4)
      col_phase<4,0,true,false>(X, D, ca_w + (size_t)l*3*D*D, D, bk*4,
          ca_b + (size_t)l*3*D, true, ln2g + l*D, ln2b + l*D,
          Qd, D, nullptr, nullptr, nullptr, 0, nullptr, LB, t);
      gsync(bar, ++tgt);
      // 5: cross-attn
      attn2(Qd, cb_, cb_ + D, 1024, M, ATd, r_at, hh, LB, t);
      gsync(bar, ++tgt);
      // 6: cross out-proj + res (CN=4)
      col_phase<4,2,false,false>(ATd, D, ca_ow + (size_t)l*D*D, D, bk*4,
          ca_ob + (size_t)l*D, true, nullptr, nullptr,
          nullptr, 0, nullptr, nullptr, nullptr, 0, X, LB, t);
      gsync(bar, ++tgt);
      // 7: LN3 + FFN1 + GELU (CN=16)
      col_phase<16,0,true,true>(X, D, fw1 + (size_t)l*2048*D, D, bk*16,
          fb1 + (size_t)l*2048, true, ln3g + l*D, ln3b + l*D,
          HH, 2048, nullptr, nullptr, nullptr, 0, nullptr, LB, t);
      gsync(bar, ++tgt);
      // 8: FFN2 K-split (32 col-groups x 4 K-slices), atomicAdd + res
      {
        int cg = bk & 31, sl = bk >> 5;
        col_phase<16,3,false,false>(HH + sl*512, 2048,
            fw2 + (size_t)l*D*2048 + (size_t)sl*512, 2048, cg*16,
            fb2 + (size_t)l*D, (sl == 0), nullptr, nullptr,
            nullptr, 0, nullptr, nullptr, nullptr, 0, X, LB, t);
      }
      gsync(bar, ++tgt);
    }
    fin2(X, outw, outb, pos, out, st, M + st, bk, actrow, t);
    gsync(bar, ++tgt);
  }
}

// -------------------- host --------------------

extern "C" void kernel_launch(void* const* d_in, const int* in_sizes, int n_in,
                              void* d_out, int out_size, void* d_ws, size_t ws_size,
                              hipStream_t stream){
  (void)in_sizes; (void)n_in; (void)out_size; (void)ws_size;
  const float* ctx   = (const float*)d_in[0];
  const float* pos   = (const float*)d_in[1];
  const float* sa_w  = (const float*)d_in[2];
  const float* sa_b  = (const float*)d_in[3];
  const float* sa_ow = (const float*)d_in[4];
  const float* sa_ob = (const float*)d_in[5];
  const float* ca_w  = (const float*)d_in[6];
  const float* ca_b  = (const float*)d_in[7];
  const float* ca_ow = (const float*)d_in[8];
  const float* ca_ob = (const float*)d_in[9];
  const float* ln1g  = (const float*)d_in[10];
  const float* ln1b  = (const float*)d_in[11];
  const float* ln2g  = (const float*)d_in[12];
  const float* ln2b  = (const float*)d_in[13];
  const float* ln3g  = (const float*)d_in[14];
  const float* ln3b  = (const float*)d_in[15];
  const float* fw1   = (const float*)d_in[16];
  const float* fb1   = (const float*)d_in[17];
  const float* fw2   = (const float*)d_in[18];
  const float* fb2   = (const float*)d_in[19];
  const float* outw  = (const float*)d_in[20];
  const float* outb  = (const float*)d_in[21];
  float* out = (float*)d_out;

  float* w = (float*)d_ws;
  size_t off = 0;
  auto alloc = [&](size_t n){ float* p = w + off; off += n; return p; };
  float* kcache = alloc((size_t)NL*NB*SMAX*D);
  float* vcache = alloc((size_t)NL*NB*SMAX*D);
  float* ckv    = alloc((size_t)NL*NB*M*1024);
  float* X0     = alloc((size_t)NR*D);
  float* XN0    = alloc((size_t)NR*D);
  float* Q0     = alloc((size_t)NR*D);
  float* AT0    = alloc((size_t)NR*D);
  float* H0     = alloc((size_t)NR*2048);
  float* Xd     = alloc((size_t)NB*D);
  float* Qd     = alloc((size_t)NB*D);
  float* ATd    = alloc((size_t)NB*D);
  float* HHd    = alloc((size_t)NB*2048);
  unsigned* bar = (unsigned*)(w + off); off += 256;

  hipMemsetAsync(bar, 0, 1024, stream);

  dim3 blk(256);

  k_embed<<<NR, blk, 0, stream>>>(ctx, pos, X0);
  for (int l = 0; l < NL; l++){
    k_gemm<<<dim3(NR/64, 1024/64), blk, 0, stream>>>(
        ctx, ca_w + (size_t)l*3*D*D + (size_t)D*D, ca_b + (size_t)l*3*D + D, nullptr,
        ckv + (size_t)l*NB*M*1024, 512, 1024, 0, nullptr, nullptr, nullptr, GM_PLAIN);
  }

  for (int l = 0; l < NL; l++){
    const float* saw = sa_w + (size_t)l*3*D*D;
    const float* sab = sa_b + (size_t)l*3*D;
    float* kcl = kcache + (size_t)l*NB*SMAX*D;
    float* vcl = vcache + (size_t)l*NB*SMAX*D;
    const float* ckl = ckv + (size_t)l*NB*M*1024;

    k_ln<<<NR, blk, 0, stream>>>(X0, XN0, ln1g + l*D, ln1b + l*D);
    k_gemm<<<dim3(NR/64, 1536/64), blk, 0, stream>>>(
        XN0, saw, sab, nullptr, nullptr, 512, D, 0, Q0, kcl, vcl, GM_QKV);
    k_sattn_pre<<<NB*H, blk, 0, stream>>>(Q0, kcl, vcl, AT0);
    k_gemm<<<dim3(NR/64, D/64), blk, 0, stream>>>(
        AT0, sa_ow + (size_t)l*D*D, sa_ob + l*D, X0, X0, 512, D, 0,
        nullptr, nullptr, nullptr, GM_PLAIN);
    k_ln<<<NR, blk, 0, stream>>>(X0, XN0, ln2g + l*D, ln2b + l*D);
    k_gemm<<<dim3(NR/64, D/64), blk, 0, stream>>>(
        XN0, ca_w + (size_t)l*3*D*D, ca_b + (size_t)l*3*D, nullptr, Q0, 512, D, 0,
        nullptr, nullptr, nullptr, GM_PLAIN);
    k_cattn_pre<<<NB*H, blk, 0, stream>>>(Q0, ckl, AT0);
    k_gemm<<<dim3(NR/64, D/64), blk, 0, stream>>>(
        AT0, ca_ow + (size_t)l*D*D, ca_ob + l*D, X0, X0, 512, D, 0,
        nullptr, nullptr, nullptr, GM_PLAIN);
    k_ln<<<NR, blk, 0, stream>>>(X0, XN0, ln3g + l*D, ln3b + l*D);
    k_gemm<<<dim3(NR/64, 2048/64), blk, 0, stream>>>(
        XN0, fw1 + (size_t)l*2048*D, fb1 + (size_t)l*2048, nullptr, H0, 512, 2048, 1,
        nullptr, nullptr, nullptr, GM_PLAIN);
    k_gemm<<<dim3(NR/64, D/64), blk, 0, stream>>>(
        H0, fw2 + (size_t)l*D*2048, fb2 + l*D, X0, X0, 2048, D, 0,
        nullptr, nullptr, nullptr, GM_PLAIN);
  }

  k_decode<<<NBLK, dim3(512), 0, stream>>>(
      X0, pos, sa_w, sa_b, sa_ow, sa_ob, ca_w, ca_b, ca_ow, ca_ob,
      ln1g, ln1b, ln2g, ln2b, ln3g, ln3b, fw1, fb1, fw2, fb2,
      outw, outb, kcache, vcache, ckv, Xd, Qd, ATd, HHd,
      bar, out);
}